// Round 3
// baseline (125.026 us; speedup 1.0000x reference)
//
#include <hip/hip_runtime.h>
#include <hip/hip_bf16.h>

#define BB 16
#define LL 1444
#define DD 128
#define CC 21
#define CH 19   // chunk length
#define NK 76   // number of chunks; CH*NK == LL

#define CS_ELEMS ((size_t)BB*NK*CC*DD)
#define TOT_ELEMS ((size_t)BB*CC*DD)

// K1: per-chunk per-class partial sums (fp32) + source copy-out.
// All global loads staged into registers up front; class accumulation uses
// wave-uniform scalar branches (ci is identical across the block for each row).
__global__ __launch_bounds__(128) void k1_chunk_sums(
    const float* __restrict__ src, const int* __restrict__ idx,
    float* __restrict__ cs, float* __restrict__ src_copy)
{
  __shared__ int cidx[CH];
  int b = blockIdx.x / NK, k = blockIdx.x % NK;
  int d = threadIdx.x;
  int i0 = k * CH;
  if (threadIdx.x < CH) cidx[threadIdx.x] = idx[b * LL + i0 + threadIdx.x];
  __syncthreads();

  const float* s0 = src + ((size_t)(b * LL + i0)) * DD + d;
  float v[CH];
#pragma unroll
  for (int t = 0; t < CH; ++t) v[t] = s0[(size_t)t * DD];

  float* c0 = src_copy + ((size_t)(b * LL + i0)) * DD + d;
#pragma unroll
  for (int t = 0; t < CH; ++t) c0[(size_t)t * DD] = v[t];

  float acc[CC];
#pragma unroll
  for (int c = 0; c < CC; ++c) acc[c] = 0.f;

#pragma unroll
  for (int t = 0; t < CH; ++t) {
    int sci = __builtin_amdgcn_readfirstlane(cidx[t]);  // wave-uniform class
#pragma unroll
    for (int c = 0; c < CC; ++c)
      if (sci == c) acc[c] += v[t];   // scalar branch, single v_add executes
  }

  float* o = cs + ((size_t)(b * NK + k)) * CC * DD + d;
#pragma unroll
  for (int c = 0; c < CC; ++c) o[(size_t)c * DD] = acc[c];
}

// K2: exclusive scan over NK chunks for each (b,c); register-resident.
__global__ __launch_bounds__(128) void k2_scan(
    float* __restrict__ cs, float* __restrict__ tot)
{
  int b = blockIdx.x / CC, c = blockIdx.x % CC;
  int d = threadIdx.x;
  float* base = cs + ((size_t)b * NK * CC + c) * DD + d;
  float vals[NK];
#pragma unroll
  for (int k = 0; k < NK; ++k) vals[k] = base[(size_t)k * CC * DD];  // all loads issue up front
  float run = 0.f;
#pragma unroll
  for (int k = 0; k < NK; ++k) {
    float t = vals[k];
    base[(size_t)k * CC * DD] = run;
    run += t;
  }
  tot[((size_t)(b * CC + c)) * DD + d] = run;
}

// K4: fused output. R computed inline (into LDS), Q rows accessed via
// v_readlane (class index is wave-uniform), prefix update via scalar branch.
__global__ __launch_bounds__(128) void k4_fused(
    const float* __restrict__ src, const int* __restrict__ idx,
    const float* __restrict__ P, const float* __restrict__ cs,
    const float* __restrict__ tot, float* __restrict__ out)
{
  __shared__ float Qs[CC * CC];
  __shared__ float Ss[CC];
  __shared__ float Rl[CC][DD];
  __shared__ int cidx[CH];

  int b = blockIdx.x / NK, k = blockIdx.x % NK;
  int d = threadIdx.x;
  int i0 = k * CH;

  for (int t = threadIdx.x; t < CC * CC; t += 128) {
    int a = t / CC, c = t % CC;
    Qs[t] = P[a * CC + c] - P[c * CC + a];
  }
  if (threadIdx.x < CC) {
    int a = threadIdx.x;
    Ss[a] = (a != 0 ? 1.0f : 0.0f) - P[a * CC + a];
  }
  if (threadIdx.x < CH) cidx[threadIdx.x] = idx[b * LL + i0 + threadIdx.x];

  // R[a][d] = sum_c P[c][a] * Tot[b][c][d]; P indices are compile-time
  // constants -> scalar loads.
  float tt[CC];
#pragma unroll
  for (int c = 0; c < CC; ++c) tt[c] = tot[((size_t)(b * CC + c)) * DD + d];
#pragma unroll
  for (int a = 0; a < CC; ++a) {
    float r = 0.f;
#pragma unroll
    for (int c = 0; c < CC; ++c) r += P[c * CC + a] * tt[c];
    Rl[a][d] = r;
  }

  // prefix state and staged source rows
  float pre[CC];
  const float* csb = cs + ((size_t)(b * NK + k)) * CC * DD + d;
#pragma unroll
  for (int c = 0; c < CC; ++c) pre[c] = csb[(size_t)c * DD];

  const float* s0 = src + ((size_t)(b * LL + i0)) * DD + d;
  float v[CH];
#pragma unroll
  for (int t = 0; t < CH; ++t) v[t] = s0[(size_t)t * DD];

  __syncthreads();

  // Q columns distributed across lanes: lane a holds Q[a][c] in qcol[c]
  int lane = threadIdx.x & 63;
  float qcol[CC];
#pragma unroll
  for (int c = 0; c < CC; ++c) qcol[c] = (lane < CC) ? Qs[lane * CC + c] : 0.f;

  float* o0 = out + ((size_t)(b * LL + i0)) * DD + d;
#pragma unroll
  for (int t = 0; t < CH; ++t) {
    int sci = __builtin_amdgcn_readfirstlane(cidx[t]);  // wave-uniform
    float acc = Rl[sci][d] + Ss[sci] * v[t];
#pragma unroll
    for (int c = 0; c < CC; ++c) {
      float q = __uint_as_float(__builtin_amdgcn_readlane(__float_as_uint(qcol[c]), sci));
      acc += q * pre[c];
    }
    o0[(size_t)t * DD] = acc;
#pragma unroll
    for (int c = 0; c < CC; ++c)
      if (sci == c) pre[c] += v[t];   // scalar branch, single v_add
  }
}

extern "C" void kernel_launch(void* const* d_in, const int* in_sizes, int n_in,
                              void* d_out, int out_size, void* d_ws, size_t ws_size,
                              hipStream_t stream) {
  const float* P   = (const float*)d_in[0];   // cls_r_prob (C*C)
  const float* src = (const float*)d_in[1];   // source (B*L*D)
  const int*   idx = (const int*)d_in[2];     // class_idx (B*L)

  float* out_fused = (float*)d_out;                      // first B*L*D
  float* out_src   = out_fused + (size_t)BB * LL * DD;   // second B*L*D

  float* cs  = (float*)d_ws;           // [B][NK][C][D]
  float* tot = cs + CS_ELEMS;          // [B][C][D]

  k1_chunk_sums<<<BB * NK, 128, 0, stream>>>(src, idx, cs, out_src);
  k2_scan<<<BB * CC, 128, 0, stream>>>(cs, tot);
  k4_fused<<<BB * NK, 128, 0, stream>>>(src, idx, P, cs, tot, out_fused);
}